// Round 6
// baseline (1483.851 us; speedup 1.0000x reference)
//
#include <hip/hip_runtime.h>

#define T_ 512
#define B_ 256
#define H_ 512
#define NBINS 4112  // 8 groups x 514 buckets
typedef __bf16 bf16_t;
typedef __bf16 bf16x8 __attribute__((ext_vector_type(8)));
typedef float f32x4 __attribute__((ext_vector_type(4)));

// ---------------------------------------------------------------------------
__device__ __forceinline__ float bf2f(unsigned short u) {
  unsigned x = ((unsigned)u) << 16; float f; __builtin_memcpy(&f, &x, 4); return f;
}
__device__ __forceinline__ bf16x8 pack2(f32x4 a, f32x4 b) {
  bf16x8 w;
#pragma unroll
  for (int i = 0; i < 4; ++i) { w[i] = (bf16_t)a[i]; w[i + 4] = (bf16_t)b[i]; }
  return w;
}
__device__ __forceinline__ void st_sc1(float* p, float v) {
  asm volatile("global_store_dword %0, %1, off sc0 sc1" :: "v"(p), "v"(v) : "memory");
}
// 8 device-coherent 16B loads; wait INSIDE the asm (no split liveness — the
// r5 issue/wait split corrupted pending registers via spills under pressure).
__device__ __forceinline__ void ld8_sc1(const float* p0, const float* p1,
                                        const float* p2, const float* p3,
                                        const float* p4, const float* p5,
                                        const float* p6, const float* p7,
                                        f32x4& v0, f32x4& v1, f32x4& v2, f32x4& v3,
                                        f32x4& v4, f32x4& v5, f32x4& v6, f32x4& v7) {
  asm volatile(
      "global_load_dwordx4 %0, %8, off sc0 sc1\n\t"
      "global_load_dwordx4 %1, %9, off sc0 sc1\n\t"
      "global_load_dwordx4 %2, %10, off sc0 sc1\n\t"
      "global_load_dwordx4 %3, %11, off sc0 sc1\n\t"
      "global_load_dwordx4 %4, %12, off sc0 sc1\n\t"
      "global_load_dwordx4 %5, %13, off sc0 sc1\n\t"
      "global_load_dwordx4 %6, %14, off sc0 sc1\n\t"
      "global_load_dwordx4 %7, %15, off sc0 sc1\n\t"
      "s_waitcnt vmcnt(0)"
      : "=&v"(v0), "=&v"(v1), "=&v"(v2), "=&v"(v3),
        "=&v"(v4), "=&v"(v5), "=&v"(v6), "=&v"(v7)
      : "v"(p0), "v"(p1), "v"(p2), "v"(p3), "v"(p4), "v"(p5), "v"(p6), "v"(p7)
      : "memory");
}
__device__ __forceinline__ float sigm(float x) { return 1.f / (1.f + __expf(-x)); }
__device__ __forceinline__ float tanh_(float a) { return 1.f - 2.f / (__expf(2.f * a) + 1.f); }

// ---------------------------------------------------------------------------
__global__ __launch_bounds__(64) void zero_meta(int* __restrict__ flags,
                                                int* __restrict__ bar) {
  int i = threadIdx.x;
  if (i < 4) flags[i] = 0;
  if (i < 8) bar[i] = 0;
}

__global__ __launch_bounds__(256) void detect_resets(const void* __restrict__ rst,
                                                     int n, int* __restrict__ flags) {
  const int* pi = (const int*)rst;
  const float* pf = (const float*)rst;
  int a = 0, bq = 0, c = 0;
  int nq = n >> 2;
  for (int i = blockIdx.x * 256 + threadIdx.x; i < nq; i += gridDim.x * 256) {
    int v = pi[i];
    if (v != 0 && v != 1) a = 1;
    float f = pf[i];
    if (!(f == 0.0f || f == 1.0f)) bq = 1;
    if ((i & 1) && v != 0) c = 1;
  }
  if (a) atomicOr(&flags[0], 1);
  if (bq) atomicOr(&flags[1], 1);
  if (c) atomicOr(&flags[2], 1);
}

__global__ __launch_bounds__(256) void convert_resets(const void* __restrict__ rst,
                                                      const int* __restrict__ flags,
                                                      unsigned char* __restrict__ r8,
                                                      int n) {
  const int* pi = (const int*)rst;
  const float* pf = (const float*)rst;
  int mode;
  if (flags[0] == 0) mode = flags[2] ? 0 : 3;  // int32 / int64
  else if (flags[1] == 0) mode = 1;            // f32
  else mode = 2;                               // bytes
  for (int i = blockIdx.x * 256 + threadIdx.x; i < n; i += gridDim.x * 256) {
    unsigned char v;
    if (mode == 0)      v = (unsigned char)(pi[i] != 0);
    else if (mode == 3) v = (unsigned char)(pi[2 * i] != 0);
    else if (mode == 1) v = (unsigned char)(pf[i] != 0.0f);
    else                v = ((const unsigned char*)rst)[i] ? 1 : 0;
    r8[i] = v;
  }
}

// Wc[koct 0..127][n 0..1535][8 bf16]: koct<64 -> Wi[koct*8+e][n]; else Wh.
__global__ __launch_bounds__(256) void build_wc(const float* __restrict__ Wi,
                                                const float* __restrict__ Wh,
                                                bf16_t* __restrict__ Wc) {
  int id = blockIdx.x * 256 + threadIdx.x;  // 0..196607
  int koct = id / 1536, n = id % 1536;
  const float* src = (koct < 64) ? Wi : Wh;
  int kk = (koct & 63) * 8;
  bf16x8 w;
#pragma unroll
  for (int e = 0; e < 8; ++e) w[e] = (bf16_t)src[(size_t)(kk + e) * 1536 + n];
  *(bf16x8*)(Wc + (size_t)id * 8) = w;
}

// bucket: p==0 -> (t==0 && !reset) ? 1 : 0; else p+1.  bin = (b>>5)*514 + bk.
__device__ __forceinline__ int bucket_of(int t, int rs, int& p) {
  p = (t == 0 || rs) ? 0 : p + 1;
  return (p > 0) ? (p + 1) : ((t == 0 && !rs) ? 1 : 0);
}

// Merged count + scan + scatter. 1 block x 1024 threads, 64KB dyn LDS.
__global__ __launch_bounds__(1024) void bins_kernel(const unsigned char* __restrict__ r8,
                                                    int* __restrict__ cur,
                                                    unsigned int* __restrict__ elem) {
  extern __shared__ int sm[];  // 2 x 8192
  int* s0 = sm;
  int* s1 = sm + 8192;
  const int tid = threadIdx.x;
  for (int i = tid; i < 8192; i += 1024) s0[i] = 0;
  __syncthreads();
  if (tid < 256) {
    int b = tid, base = (b >> 5) * 514, p = 0;
    for (int t = 0; t < T_; ++t) {
      int bk = bucket_of(t, r8[t * B_ + b], p);
      atomicAdd(&s0[base + bk], 1);
    }
  }
  __syncthreads();
  int* a = s0;
  int* bb = s1;
  for (int d = 1; d < 8192; d <<= 1) {
    for (int i = tid; i < 8192; i += 1024) bb[i] = a[i] + ((i >= d) ? a[i - d] : 0);
    __syncthreads();
    int* t = a; a = bb; bb = t;
  }
  // a = inclusive scan; exclusive to global and to bb for live cursors
  for (int i = tid; i <= NBINS; i += 1024) cur[i] = (i == 0) ? 0 : a[i - 1];
  for (int i = tid; i < 8192; i += 1024)
    bb[i] = (i == 0) ? 0 : ((i <= NBINS) ? a[i - 1] : 0);
  __syncthreads();
  if (tid < 256) {
    int b = tid, base = (b >> 5) * 514, p = 0;
    for (int t = 0; t < T_; ++t) {
      int bk = bucket_of(t, r8[t * B_ + b], p);
      int pos = atomicAdd(&bb[base + bk], 1);
      elem[pos] = (unsigned)(t * B_ + b);
    }
  }
}

// ---------------------------------------------------------------------------
// MFMA core (proven r4): lds A tile (bf16, stride LDB, XOR-swizzled 16B
// granules); Wc streamed. q-triple = cols {j,512+j,1024+j}, j=q*16+am.
// ks<16 -> gate2 into acc[2] (nx); ks>=16 -> acc[3] (nh).
// ---------------------------------------------------------------------------
template <int NKS, int NRGC, int LDB>
__device__ __forceinline__ void mm_block(const char* lds, const char* W, int q,
                                         int rgb, int span, int nrgd, int am, int aq,
                                         f32x4 (&acc)[4][NRGC]) {
  const char* Bp = W + (size_t)(q * 16 + am) * 16;
#pragma unroll
  for (int ks = 0; ks < NKS; ++ks) {
    const int koct = ks * 4 + aq;
    const char* bb = Bp + (size_t)koct * 24576;
    bf16x8 b0 = *(const bf16x8*)(bb);
    bf16x8 b1 = *(const bf16x8*)(bb + 8192);
    bf16x8 b2 = *(const bf16x8*)(bb + 16384);
#pragma unroll
    for (int rg = 0; rg < NRGC; ++rg) {
      if (rg >= rgb && rg < rgb + span && rg < nrgd) {
        const int ar = rg * 16 + am;
        bf16x8 af = *(const bf16x8*)(lds + (size_t)ar * LDB +
                                     ((koct * 16) ^ ((ar & 7) << 4)));
        acc[0][rg] = __builtin_amdgcn_mfma_f32_16x16x32_bf16(af, b0, acc[0][rg], 0, 0, 0);
        acc[1][rg] = __builtin_amdgcn_mfma_f32_16x16x32_bf16(af, b1, acc[1][rg], 0, 0, 0);
        if (ks < 16)
          acc[2][rg] = __builtin_amdgcn_mfma_f32_16x16x32_bf16(af, b2, acc[2][rg], 0, 0, 0);
        else
          acc[3][rg] = __builtin_amdgcn_mfma_f32_16x16x32_bf16(af, b2, acc[3][rg], 0, 0, 0);
      }
    }
  }
}

// ---------------------------------------------------------------------------
// Cooperative phase sweep. 8 groups x 32 blocks; group g owns batch rows
// [32g,32g+32). it=0: bucket0 (reset rows, h==0) as 128-row x-only tiles.
// it=1: bucket1 (t=0 non-reset, h=h0). it>=2: phase it-1. Spin barrier per
// group (no L2 flush); h-state via sc0/sc1; x via nontemporal loads.
// ---------------------------------------------------------------------------
__global__ __launch_bounds__(512, 2) void gru_phases(
    const float* __restrict__ ins, const float* __restrict__ h0,
    const bf16_t* __restrict__ Wc, const float* __restrict__ bi,
    const float* __restrict__ bhn, const unsigned int* __restrict__ elem,
    const int* __restrict__ cur, int* __restrict__ bar, float* __restrict__ out) {
  extern __shared__ char lds[];
  const int tid = threadIdx.x, lane = tid & 63, w = tid >> 6;
  const int am = lane & 15, aq = lane >> 4;
  const int g = blockIdx.x >> 5, bg = blockIdx.x & 31;
  const int base = g * 514;

  for (int it = 0; it <= 513; ++it) {
    const int beg = cur[base + it];
    const int cnt = cur[base + it + 1] - beg;
    if (it >= 2 && cnt == 0) break;
    if (cnt > 0 && it == 0) {
      // ================= it=0: x-only, 128-row tiles =================
      const int ntiles = (cnt + 127) >> 7;
      for (int u = bg; u < ntiles; u += 32) {
        __syncthreads();
        {  // stage 128 rows x 512 f32 -> bf16 (LDB=1024)
          const int tr = tid >> 2, tl = tid & 3;
          const int row = u * 128 + tr;
          const float* xs = (row < cnt) ? (ins + (size_t)elem[beg + row] * 512) : nullptr;
          const int swz = (tr & 7) << 4;
          char* lrp = lds + tr * 1024;
#pragma unroll 4
          for (int s2 = 0; s2 < 16; ++s2) {
            const int ko = tl + 4 * s2;
            bf16x8 wv;
            if (xs) {
              f32x4 a0 = __builtin_nontemporal_load((const f32x4*)(xs + ko * 8));
              f32x4 a1 = __builtin_nontemporal_load((const f32x4*)(xs + ko * 8 + 4));
              wv = pack2(a0, a1);
            } else {
#pragma unroll
              for (int z = 0; z < 8; ++z) wv[z] = (bf16_t)0.f;
            }
            *(bf16x8*)(lrp + ((ko * 16) ^ swz)) = wv;
          }
        }
        __syncthreads();
        const int rem = cnt - u * 128;
        const int nrgd = ((rem < 128 ? rem : 128) + 15) >> 4;
#pragma unroll 1
        for (int s = 0; s < 4; ++s) {
          const int q = w + 8 * s;
          f32x4 acc[4][8];
#pragma unroll
          for (int gg = 0; gg < 4; ++gg)
#pragma unroll
            for (int r = 0; r < 8; ++r) acc[gg][r] = (f32x4){0.f, 0.f, 0.f, 0.f};
          mm_block<16, 8, 1024>(lds, (const char*)Wc, q, 0, 8, nrgd, am, aq, acc);
          const int j = q * 16 + am;
          const float bir = bi[j], biz = bi[512 + j], bin = bi[1024 + j], bh = bhn[j];
#pragma unroll
          for (int rg = 0; rg < 8; ++rg) {
            if (rg < nrgd) {
#pragma unroll
              for (int qq = 0; qq < 4; ++qq) {
                const int row = u * 128 + rg * 16 + aq * 4 + qq;
                if (row < cnt) {
                  float r = sigm(acc[0][rg][qq] + bir);
                  float z = sigm(acc[1][rg][qq] + biz);
                  float n = tanh_(acc[2][rg][qq] + bin + r * bh);
                  st_sc1(out + (size_t)elem[beg + row] * 512 + j, (1.f - z) * n);
                }
              }
            }
          }
        }
      }
    } else if (cnt > 0) {
      // ================= it>=1: full-K, 64-row tiles, jsplit =================
      const int ntiles = (cnt + 63) >> 6;
      int lg = 0;
      while (lg < 4 && (ntiles << lg) < 32) ++lg;
      const int nitems = ntiles << lg;
      const int Q = 32 >> lg;
      for (int i = bg; i < nitems; i += 32) {
        const int u = i >> lg, jc = i & ((1 << lg) - 1);
        __syncthreads();
        {  // stage 64 rows x (512 x | 512 h); x nt-cached, h sc1 (waits inside)
          const int tr = tid >> 3, tl = tid & 7;
          const int row = u * 64 + tr;
          const float* xs = nullptr;
          const float* ph = nullptr;
          if (row < cnt) {
            const unsigned e = elem[beg + row];
            xs = ins + (size_t)e * 512;
            ph = (e < 256) ? (h0 + (size_t)e * 512) : (out + ((size_t)e - 256) * 512);
          }
          const int swz = (tr & 7) << 4;
          char* lrp = lds + tr * 2048;
          // x half (compiler-managed loads; it can batch/pipeline these)
#pragma unroll
          for (int s2 = 0; s2 < 8; ++s2) {
            const int ko = tl + 8 * s2;
            bf16x8 wv;
            if (xs) {
              f32x4 a0 = __builtin_nontemporal_load((const f32x4*)(xs + ko * 8));
              f32x4 a1 = __builtin_nontemporal_load((const f32x4*)(xs + ko * 8 + 4));
              wv = pack2(a0, a1);
            } else {
#pragma unroll
              for (int z = 0; z < 8; ++z) wv[z] = (bf16_t)0.f;
            }
            *(bf16x8*)(lrp + ((ko * 16) ^ swz)) = wv;
          }
          // h half: 2 batches of 8 coherent loads, wait inside each asm block
          if (ph) {
#pragma unroll 1
            for (int hb = 0; hb < 2; ++hb) {
              f32x4 hv[8];
              const float* hp[8];
#pragma unroll
              for (int s2 = 0; s2 < 4; ++s2) {
                const int ko = tl + 8 * (8 + hb * 4 + s2);
                hp[2 * s2] = ph + (ko & 63) * 8;
                hp[2 * s2 + 1] = ph + (ko & 63) * 8 + 4;
              }
              ld8_sc1(hp[0], hp[1], hp[2], hp[3], hp[4], hp[5], hp[6], hp[7],
                      hv[0], hv[1], hv[2], hv[3], hv[4], hv[5], hv[6], hv[7]);
#pragma unroll
              for (int s2 = 0; s2 < 4; ++s2) {
                const int ko = tl + 8 * (8 + hb * 4 + s2);
                *(bf16x8*)(lrp + ((ko * 16) ^ swz)) = pack2(hv[2 * s2], hv[2 * s2 + 1]);
              }
            }
          } else {
#pragma unroll
            for (int s2 = 0; s2 < 8; ++s2) {
              const int ko = tl + 8 * (8 + s2);
              bf16x8 wv;
#pragma unroll
              for (int z = 0; z < 8; ++z) wv[z] = (bf16_t)0.f;
              *(bf16x8*)(lrp + ((ko * 16) ^ swz)) = wv;
            }
          }
        }
        __syncthreads();
        const int rem = cnt - u * 64;
        const int nrgd = ((rem < 64 ? rem : 64) + 15) >> 4;
        const int span = (Q >= 8) ? 4 : (Q >> 1);
        const int rgb = (Q >= 8) ? 0 : (w / Q) * span;
        const int nq = (Q >= 8) ? (Q >> 3) : 1;
#pragma unroll 1
        for (int s = 0; s < nq; ++s) {
          const int q = (Q >= 8) ? (jc * Q + w + 8 * s) : (jc * Q + (w & (Q - 1)));
          f32x4 acc[4][4];
#pragma unroll
          for (int gg = 0; gg < 4; ++gg)
#pragma unroll
            for (int r = 0; r < 4; ++r) acc[gg][r] = (f32x4){0.f, 0.f, 0.f, 0.f};
          mm_block<32, 4, 2048>(lds, (const char*)Wc, q, rgb, span, nrgd, am, aq, acc);
          const int j = q * 16 + am;
          const float bir = bi[j], biz = bi[512 + j], bin = bi[1024 + j], bh = bhn[j];
#pragma unroll
          for (int rg = 0; rg < 4; ++rg) {
            if (rg >= rgb && rg < rgb + span && rg < nrgd) {
#pragma unroll
              for (int qq = 0; qq < 4; ++qq) {
                const int lrow = rg * 16 + aq * 4 + qq;
                const int row = u * 64 + lrow;
                if (row < cnt) {
                  const unsigned e = elem[beg + row];
                  unsigned short hraw = *(const unsigned short*)(
                      lds + (size_t)lrow * 2048 +
                      (((64 + (j >> 3)) * 16) ^ ((lrow & 7) << 4)) + (j & 7) * 2);
                  float hp = bf2f(hraw);
                  float r = sigm(acc[0][rg][qq] + bir);
                  float z = sigm(acc[1][rg][qq] + biz);
                  float n = tanh_(acc[2][rg][qq] + bin + r * (acc[3][rg][qq] + bh));
                  st_sc1(out + (size_t)e * 512 + j, (1.f - z) * n + z * hp);
                }
              }
            }
          }
        }
      }
    }
    // group barrier: no device-scope fence, no L2 flush
    __syncthreads();
    if (tid == 0) {
      __hip_atomic_fetch_add(&bar[g], 1, __ATOMIC_RELAXED, __HIP_MEMORY_SCOPE_AGENT);
      const int target = 32 * (it + 1);
      while (__hip_atomic_load(&bar[g], __ATOMIC_RELAXED, __HIP_MEMORY_SCOPE_AGENT) <
             target) {
        __builtin_amdgcn_s_sleep(2);
      }
    }
    __syncthreads();
  }
}

// ---------------------------------------------------------------------------
extern "C" void kernel_launch(void* const* d_in, const int* in_sizes, int n_in,
                              void* d_out, int out_size, void* d_ws, size_t ws_size,
                              hipStream_t stream) {
  const float* h0  = (const float*)d_in[0];
  const float* ins = (const float*)d_in[1];
  const float* Wi  = (const float*)d_in[2];
  const float* bi  = (const float*)d_in[3];
  const float* Wh  = (const float*)d_in[4];
  const float* bhn = (const float*)d_in[5];
  const void*  rst = d_in[6];
  float* out = (float*)d_out;

  char* ws = (char*)d_ws;
  const size_t off_r8    = 0;         // 131072
  const size_t off_Wc    = 131072;    // 3145728
  const size_t off_flags = 3276800;   // 64
  const size_t off_bar   = 3276864;   // 64
  const size_t off_cur   = 3276928;   // 16512
  const size_t off_elem  = 3293440;   // 524288
  const size_t need      = 3817728;
  if (ws_size < need) return;  // loud failure

  unsigned char* r8 = (unsigned char*)(ws + off_r8);
  bf16_t* Wc = (bf16_t*)(ws + off_Wc);
  int* flags = (int*)(ws + off_flags);
  int* bar = (int*)(ws + off_bar);
  int* cur = (int*)(ws + off_cur);
  unsigned int* elem = (unsigned int*)(ws + off_elem);

  zero_meta<<<1, 64, 0, stream>>>(flags, bar);
  detect_resets<<<64, 256, 0, stream>>>(rst, T_ * B_, flags);
  convert_resets<<<128, 256, 0, stream>>>(rst, flags, r8, T_ * B_);
  build_wc<<<768, 256, 0, stream>>>(Wi, Wh, Wc);
  (void)hipFuncSetAttribute((const void*)bins_kernel,
                            hipFuncAttributeMaxDynamicSharedMemorySize, 65536);
  bins_kernel<<<1, 1024, 65536, stream>>>(r8, cur, elem);

  (void)hipFuncSetAttribute((const void*)gru_phases,
                            hipFuncAttributeMaxDynamicSharedMemorySize, 131072);
  void* args[] = {(void*)&ins, (void*)&h0, (void*)&Wc, (void*)&bi, (void*)&bhn,
                  (void*)&elem, (void*)&cur, (void*)&bar, (void*)&out};
  (void)hipLaunchCooperativeKernel((const void*)gru_phases, dim3(256), dim3(512),
                                   args, 131072, stream);
}